// Round 1
// baseline (592.214 us; speedup 1.0000x reference)
//
#include <hip/hip_runtime.h>
#include <hip/hip_bf16.h>
#include <math.h>

#define BATCH  4
#define SEQ    2048
#define DMODEL 256
#define NH     8
#define DH     32
#define MTOT   (BATCH*SEQ)   // 8192
#define SCALE  0.0625f       // 256^-0.5 (full dim, per reference)

// ---------------------------------------------------------------------------
// Kernel 1: QKV projection.  x[8192,256] @ w[256,768] + bias -> q,k,v each in
// [b,h,n,dh] layout.  Tile 128x64, BK=32, 256 threads, 8x4 per thread.
// A tile stored transposed in LDS (pad 132) so per-kk A reads are 2x b128.
// ---------------------------------------------------------------------------
__global__ __launch_bounds__(256) void qkv_gemm(
    const float* __restrict__ x, const float* __restrict__ w,
    const float* __restrict__ bias,
    float* __restrict__ qo, float* __restrict__ ko, float* __restrict__ vo)
{
    __shared__ float At[32][132];   // [k][row], pad keeps 16B align + spreads banks
    __shared__ float Bs[32][64];
    const int tid  = threadIdx.x;
    const int tx   = tid & 15;      // col group (4 cols)
    const int ty   = tid >> 4;      // row group (8 rows)
    const int row0 = blockIdx.y * 128;
    const int col0 = blockIdx.x * 64;

    float acc[8][4];
#pragma unroll
    for (int i = 0; i < 8; ++i)
#pragma unroll
        for (int j = 0; j < 4; ++j) acc[i][j] = 0.f;

    for (int k0 = 0; k0 < DMODEL; k0 += 32) {
        __syncthreads();
#pragma unroll
        for (int jj = 0; jj < 4; ++jj) {           // A: 128x32 = 1024 float4
            int f  = tid + 256 * jj;
            int rl = f >> 3;
            int c4 = (f & 7) << 2;
            float4 t = *(const float4*)(x + (size_t)(row0 + rl) * DMODEL + k0 + c4);
            At[c4 + 0][rl] = t.x; At[c4 + 1][rl] = t.y;
            At[c4 + 2][rl] = t.z; At[c4 + 3][rl] = t.w;
        }
#pragma unroll
        for (int jj = 0; jj < 2; ++jj) {           // B: 32x64 = 512 float4
            int f  = tid + 256 * jj;
            int rl = f >> 4;
            int c4 = (f & 15) << 2;
            *(float4*)&Bs[rl][c4] =
                *(const float4*)(w + (size_t)(k0 + rl) * 768 + col0 + c4);
        }
        __syncthreads();
#pragma unroll
        for (int kk = 0; kk < 32; ++kk) {
            float4 a0 = *(const float4*)&At[kk][ty * 8];
            float4 a1 = *(const float4*)&At[kk][ty * 8 + 4];
            float4 b  = *(const float4*)&Bs[kk][tx * 4];
            float av[8] = {a0.x, a0.y, a0.z, a0.w, a1.x, a1.y, a1.z, a1.w};
            float bv[4] = {b.x, b.y, b.z, b.w};
#pragma unroll
            for (int i = 0; i < 8; ++i)
#pragma unroll
                for (int j = 0; j < 4; ++j) acc[i][j] += av[i] * bv[j];
        }
    }
    // epilogue: scatter into q/k/v [b,h,n,dh]
#pragma unroll
    for (int i = 0; i < 8; ++i) {
        int grow = row0 + ty * 8 + i;
        int bi   = grow >> 11;        // /2048
        int n    = grow & 2047;
#pragma unroll
        for (int j = 0; j < 4; ++j) {
            int col   = col0 + tx * 4 + j;
            float v   = acc[i][j] + bias[col];
            int which = col >> 8;     // 0=q 1=k 2=v
            int dcol  = col & 255;
            int h     = dcol >> 5;
            int dhi   = dcol & 31;
            float* base = (which == 0) ? qo : (which == 1 ? ko : vo);
            base[(((size_t)bi * NH + h) * SEQ + n) * DH + dhi] = v;
        }
    }
}

// ---------------------------------------------------------------------------
// Kernel 2: flash-style attention per (b,h).  One thread owns one q row
// (q[32], o[32] in regs).  K/V tiles of 128 rows staged in LDS; chunked
// (8-wide) online softmax to amortize the o-rescale.
// grid: (SEQ/256, NH, BATCH), block 256.
// ---------------------------------------------------------------------------
__global__ __launch_bounds__(256) void attn_kernel(
    const float* __restrict__ q_ws, const float* __restrict__ k_ws,
    const float* __restrict__ v_ws, float* __restrict__ a_ws)
{
    __shared__ float Ks[128][32];
    __shared__ float Vs[128][32];
    const int tid = threadIdx.x;
    const int h   = blockIdx.y;
    const int b   = blockIdx.z;
    const int bh  = b * NH + h;
    const int r   = blockIdx.x * 256 + tid;
    const float* qp = q_ws + ((size_t)bh * SEQ + r) * DH;
    const float* kb = k_ws + (size_t)bh * SEQ * DH;
    const float* vb = v_ws + (size_t)bh * SEQ * DH;

    float q[32], o[32];
#pragma unroll
    for (int u = 0; u < 8; ++u) {
        float4 t = ((const float4*)qp)[u];
        q[4*u] = t.x; q[4*u+1] = t.y; q[4*u+2] = t.z; q[4*u+3] = t.w;
    }
#pragma unroll
    for (int i = 0; i < 32; ++i) o[i] = 0.f;
    float m = -1e30f, l = 0.f;

    for (int kt = 0; kt < SEQ; kt += 128) {
        __syncthreads();
#pragma unroll
        for (int jj = 0; jj < 4; ++jj) {   // stage 128x32 K and V
            int f  = tid + 256 * jj;
            int rl = f >> 3;
            int c4 = (f & 7) << 2;
            *(float4*)&Ks[rl][c4] = *(const float4*)(kb + (size_t)(kt + rl) * DH + c4);
            *(float4*)&Vs[rl][c4] = *(const float4*)(vb + (size_t)(kt + rl) * DH + c4);
        }
        __syncthreads();

        for (int j0 = 0; j0 < 128; j0 += 8) {
            float s[8];
#pragma unroll
            for (int jc = 0; jc < 8; ++jc) {
                const float4* kr = (const float4*)&Ks[j0 + jc][0];
                float a0 = 0.f, a1 = 0.f, a2 = 0.f, a3 = 0.f;
#pragma unroll
                for (int u = 0; u < 8; ++u) {
                    float4 kv = kr[u];
                    a0 += q[4*u]   * kv.x; a1 += q[4*u+1] * kv.y;
                    a2 += q[4*u+2] * kv.z; a3 += q[4*u+3] * kv.w;
                }
                s[jc] = (a0 + a1 + a2 + a3) * SCALE;
            }
            float cm = s[0];
#pragma unroll
            for (int jc = 1; jc < 8; ++jc) cm = fmaxf(cm, s[jc]);
            float mn    = fmaxf(m, cm);
            float alpha = __expf(m - mn);
            m = mn;
            l *= alpha;
#pragma unroll
            for (int i = 0; i < 32; ++i) o[i] *= alpha;
#pragma unroll
            for (int jc = 0; jc < 8; ++jc) {
                float p = __expf(s[jc] - mn);
                l += p;
                const float4* vr = (const float4*)&Vs[j0 + jc][0];
#pragma unroll
                for (int u = 0; u < 8; ++u) {
                    float4 vv = vr[u];
                    o[4*u]   += p * vv.x; o[4*u+1] += p * vv.y;
                    o[4*u+2] += p * vv.z; o[4*u+3] += p * vv.w;
                }
            }
        }
    }
    float inv = 1.0f / l;
    float* op = a_ws + ((size_t)b * SEQ + r) * DMODEL + h * DH;
#pragma unroll
    for (int u = 0; u < 8; ++u) {
        ((float4*)op)[u] = make_float4(o[4*u] * inv, o[4*u+1] * inv,
                                       o[4*u+2] * inv, o[4*u+3] * inv);
    }
}

// ---------------------------------------------------------------------------
// Kernel 3: output projection. a[8192,256] @ w[256,256] + bias -> out.
// Same tiling as qkv_gemm.
// ---------------------------------------------------------------------------
__global__ __launch_bounds__(256) void out_gemm(
    const float* __restrict__ a, const float* __restrict__ w,
    const float* __restrict__ bias, float* __restrict__ out)
{
    __shared__ float At[32][132];
    __shared__ float Bs[32][64];
    const int tid  = threadIdx.x;
    const int tx   = tid & 15;
    const int ty   = tid >> 4;
    const int row0 = blockIdx.y * 128;
    const int col0 = blockIdx.x * 64;

    float acc[8][4];
#pragma unroll
    for (int i = 0; i < 8; ++i)
#pragma unroll
        for (int j = 0; j < 4; ++j) acc[i][j] = 0.f;

    for (int k0 = 0; k0 < DMODEL; k0 += 32) {
        __syncthreads();
#pragma unroll
        for (int jj = 0; jj < 4; ++jj) {
            int f  = tid + 256 * jj;
            int rl = f >> 3;
            int c4 = (f & 7) << 2;
            float4 t = *(const float4*)(a + (size_t)(row0 + rl) * DMODEL + k0 + c4);
            At[c4 + 0][rl] = t.x; At[c4 + 1][rl] = t.y;
            At[c4 + 2][rl] = t.z; At[c4 + 3][rl] = t.w;
        }
#pragma unroll
        for (int jj = 0; jj < 2; ++jj) {
            int f  = tid + 256 * jj;
            int rl = f >> 4;
            int c4 = (f & 15) << 2;
            *(float4*)&Bs[rl][c4] =
                *(const float4*)(w + (size_t)(k0 + rl) * DMODEL + col0 + c4);
        }
        __syncthreads();
#pragma unroll
        for (int kk = 0; kk < 32; ++kk) {
            float4 a0 = *(const float4*)&At[kk][ty * 8];
            float4 a1 = *(const float4*)&At[kk][ty * 8 + 4];
            float4 b  = *(const float4*)&Bs[kk][tx * 4];
            float av[8] = {a0.x, a0.y, a0.z, a0.w, a1.x, a1.y, a1.z, a1.w};
            float bv[4] = {b.x, b.y, b.z, b.w};
#pragma unroll
            for (int i = 0; i < 8; ++i)
#pragma unroll
                for (int j = 0; j < 4; ++j) acc[i][j] += av[i] * bv[j];
        }
    }
#pragma unroll
    for (int i = 0; i < 8; ++i) {
        int grow = row0 + ty * 8 + i;
        int col  = col0 + tx * 4;
        float4 t;
        t.x = acc[i][0] + bias[col + 0];
        t.y = acc[i][1] + bias[col + 1];
        t.z = acc[i][2] + bias[col + 2];
        t.w = acc[i][3] + bias[col + 3];
        *(float4*)(out + (size_t)grow * DMODEL + col) = t;
    }
}

extern "C" void kernel_launch(void* const* d_in, const int* in_sizes, int n_in,
                              void* d_out, int out_size, void* d_ws, size_t ws_size,
                              hipStream_t stream) {
    const float* x     = (const float*)d_in[0];
    const float* w_qkv = (const float*)d_in[1];
    const float* b_qkv = (const float*)d_in[2];
    const float* w_out = (const float*)d_in[3];
    const float* b_out = (const float*)d_in[4];
    float* out = (float*)d_out;

    const size_t TSZ = (size_t)MTOT * DMODEL;   // 2,097,152 floats per tensor
    float* q_ws = (float*)d_ws;
    float* k_ws = q_ws + TSZ;
    float* v_ws = k_ws + TSZ;
    float* a_ws = v_ws + TSZ;                   // total 32 MiB of d_ws

    qkv_gemm<<<dim3(768 / 64, MTOT / 128), 256, 0, stream>>>(
        x, w_qkv, b_qkv, q_ws, k_ws, v_ws);
    attn_kernel<<<dim3(SEQ / 256, NH, BATCH), 256, 0, stream>>>(
        q_ws, k_ws, v_ws, a_ws);
    out_gemm<<<dim3(DMODEL / 64, MTOT / 128), 256, 0, stream>>>(
        a_ws, w_out, b_out, out);
}

// Round 2
// 181.363 us; speedup vs baseline: 3.2654x; 3.2654x over previous
//
#include <hip/hip_runtime.h>
#include <hip/hip_bf16.h>
#include <math.h>

#define BATCH  4
#define SEQ    2048
#define DMODEL 256
#define NH     8
#define DH     32
#define MTOT   (BATCH*SEQ)   // 8192
#define SCALE  0.0625f       // 256^-0.5 (full dim, per reference)

typedef short  bf16x8 __attribute__((ext_vector_type(8)));   // 8 bf16 = 4 VGPRs
typedef float  f32x4  __attribute__((ext_vector_type(4)));

static __device__ __forceinline__ ushort f2bf(float f) {
    __hip_bfloat16 h = __float2bfloat16(f);   // RNE
    return __builtin_bit_cast(ushort, h);
}

// ---------------------------------------------------------------------------
// Kernel 1: QKV projection (fp32 compute).  x[8192,256] @ w[256,768] + bias.
// Emits bf16:  q,k in [b,h,n,dh];  V TRANSPOSED in [b,h,dh,n] so the attention
// kernel can stage V^T with contiguous b128 copies.
// Tile 128x64, BK=32, 256 threads, 8x4 per thread.  A block's 64-col span is
// entirely within one of {q,k,v} (col0 multiple of 64), so `which` is uniform.
// ---------------------------------------------------------------------------
__global__ __launch_bounds__(256) void qkv_gemm(
    const float* __restrict__ x, const float* __restrict__ w,
    const float* __restrict__ bias,
    __hip_bfloat16* __restrict__ qo, __hip_bfloat16* __restrict__ ko,
    __hip_bfloat16* __restrict__ vo)
{
    __shared__ float At[32][132];
    __shared__ float Bs[32][64];
    const int tid  = threadIdx.x;
    const int tx   = tid & 15;
    const int ty   = tid >> 4;
    const int row0 = blockIdx.y * 128;
    const int col0 = blockIdx.x * 64;

    float acc[8][4];
#pragma unroll
    for (int i = 0; i < 8; ++i)
#pragma unroll
        for (int j = 0; j < 4; ++j) acc[i][j] = 0.f;

    for (int k0 = 0; k0 < DMODEL; k0 += 32) {
        __syncthreads();
#pragma unroll
        for (int jj = 0; jj < 4; ++jj) {
            int f  = tid + 256 * jj;
            int rl = f >> 3;
            int c4 = (f & 7) << 2;
            float4 t = *(const float4*)(x + (size_t)(row0 + rl) * DMODEL + k0 + c4);
            At[c4 + 0][rl] = t.x; At[c4 + 1][rl] = t.y;
            At[c4 + 2][rl] = t.z; At[c4 + 3][rl] = t.w;
        }
#pragma unroll
        for (int jj = 0; jj < 2; ++jj) {
            int f  = tid + 256 * jj;
            int rl = f >> 4;
            int c4 = (f & 15) << 2;
            *(float4*)&Bs[rl][c4] =
                *(const float4*)(w + (size_t)(k0 + rl) * 768 + col0 + c4);
        }
        __syncthreads();
#pragma unroll
        for (int kk = 0; kk < 32; ++kk) {
            float4 a0 = *(const float4*)&At[kk][ty * 8];
            float4 a1 = *(const float4*)&At[kk][ty * 8 + 4];
            float4 b  = *(const float4*)&Bs[kk][tx * 4];
            float av[8] = {a0.x, a0.y, a0.z, a0.w, a1.x, a1.y, a1.z, a1.w};
            float bv[4] = {b.x, b.y, b.z, b.w};
#pragma unroll
            for (int i = 0; i < 8; ++i)
#pragma unroll
                for (int j = 0; j < 4; ++j) acc[i][j] += av[i] * bv[j];
        }
    }

    // ---- epilogue: bf16 emit ----
    const int col   = col0 + tx * 4;
    const int which = col >> 8;           // uniform per block
    const int dcol  = col & 255;
    const int h     = dcol >> 5;          // same for j=0..3
    const int dh0   = dcol & 31;
    const int grow0 = row0 + ty * 8;
    const int bi    = grow0 >> 11;        // uniform within thread's 8 rows
    const int n0    = grow0 & 2047;

    if (which < 2) {
        __hip_bfloat16* base = (which == 0) ? qo : ko;
#pragma unroll
        for (int i = 0; i < 8; ++i) {
            ushort4 pk;
            pk.x = f2bf(acc[i][0] + bias[col + 0]);
            pk.y = f2bf(acc[i][1] + bias[col + 1]);
            pk.z = f2bf(acc[i][2] + bias[col + 2]);
            pk.w = f2bf(acc[i][3] + bias[col + 3]);
            *(ushort4*)&base[(((size_t)bi * NH + h) * SEQ + n0 + i) * DH + dh0] = pk;
        }
    } else {
        // V^T: vo[((bi*NH+h)*DH + dh)*SEQ + n], 8 consecutive n per write
#pragma unroll
        for (int j = 0; j < 4; ++j) {
            bf16x8 t;
#pragma unroll
            for (int i = 0; i < 8; ++i)
                t[i] = (short)f2bf(acc[i][j] + bias[col + j]);
            size_t idx = (((size_t)bi * NH + h) * DH + dh0 + j) * SEQ + n0;
            *(bf16x8*)&vo[idx] = t;
        }
    }
}

// ---------------------------------------------------------------------------
// Kernel 2: MFMA flash attention.  4 waves/block, 16 q-rows/wave (64/block).
// S^T = K·Q^T per 16x16 tile (one mfma_f32_16x16x32_bf16, K-dim = dh = 32):
//   A-frag = K[seq=tile*16+(ln&15)][dh=quad*8..+7]   (contig b128 from Ks)
//   B-frag = Q[q=ln&15][dh=quad*8..+7]               (contig b128 from global)
//   C-layout: row = seq = quad*4+reg, col = q = ln&15
//   -> per-lane 32 scores are all for q=ln&15; regs = consecutive seq.
// Online softmax: within-lane + shfl_xor(16,32).  P packed bf16 -> b64 writes
// to P[q][seq]; PV A-frag reads back contiguous b128.  V^T staged [dh][seq].
// O C-layout rows are q=quad*4+reg -> alpha/l broadcast via __shfl.
// ---------------------------------------------------------------------------
#define KS_STRIDE 40    // ushorts per K row  (32 + 8 pad)
#define VT_STRIDE 136   // ushorts per V^T row (128 + 8 pad)
#define P_STRIDE  136   // ushorts per P row   (128 + 8 pad)

__global__ __launch_bounds__(256, 4) void attn_mfma(
    const ushort* __restrict__ qb, const ushort* __restrict__ kb,
    const ushort* __restrict__ vtb, float* __restrict__ a_ws)
{
    __shared__ ushort Ks[128 * KS_STRIDE];     // 10240 B
    __shared__ ushort VsT[32 * VT_STRIDE];     //  8704 B
    __shared__ ushort Pl[4 * 16 * P_STRIDE];   // 17408 B (per-wave buffers)

    const int tid  = threadIdx.x;
    const int wid  = tid >> 6;
    const int lane = tid & 63;
    const int lq   = lane & 15;
    const int quad = lane >> 4;
    const int h    = blockIdx.y;
    const int b    = blockIdx.z;
    const int bh   = b * NH + h;
    const int q0   = blockIdx.x * 64 + wid * 16;

    // Q B-frag: one-time global b128 load
    const ushort* qrow = qb + ((size_t)bh * SEQ + q0 + lq) * DH + quad * 8;
    const bf16x8 qf = *(const bf16x8*)qrow;

    const ushort* kbase  = kb  + (size_t)bh * SEQ * DH;   // [seq][dh]
    const ushort* vtbase = vtb + (size_t)bh * DH * SEQ;   // [dh][seq]
    ushort* Pw = Pl + wid * 16 * P_STRIDE;

    f32x4 o0 = {0.f, 0.f, 0.f, 0.f};
    f32x4 o1 = {0.f, 0.f, 0.f, 0.f};
    float m = -1e30f, l = 0.f;
    const float C = 0.09016844005556021f;   // SCALE * log2(e)

    for (int kt = 0; kt < SEQ; kt += 128) {
        __syncthreads();
#pragma unroll
        for (int jj = 0; jj < 2; ++jj) {
            int f = tid + 256 * jj;
            {   // K: 128 rows x 32 bf16
                int r  = f >> 2;
                int c8 = (f & 3) * 8;
                *(bf16x8*)&Ks[r * KS_STRIDE + c8] =
                    *(const bf16x8*)(kbase + (size_t)(kt + r) * DH + c8);
            }
            {   // V^T: 32 rows x 128 bf16
                int dh = f >> 4;
                int c8 = (f & 15) * 8;
                *(bf16x8*)&VsT[dh * VT_STRIDE + c8] =
                    *(const bf16x8*)(vtbase + (size_t)dh * SEQ + kt + c8);
            }
        }
        __syncthreads();

        // ---- QK^T: 8 tiles of S^T ----
        f32x4 st[8];
#pragma unroll
        for (int t = 0; t < 8; ++t) {
            bf16x8 kf = *(const bf16x8*)&Ks[(t * 16 + lq) * KS_STRIDE + quad * 8];
            f32x4 z = {0.f, 0.f, 0.f, 0.f};
            st[t] = __builtin_amdgcn_mfma_f32_16x16x32_bf16(kf, qf, z, 0, 0, 0);
        }

        // ---- online softmax over the 128-chunk (per q = lq) ----
        float cm = -1e30f;
#pragma unroll
        for (int t = 0; t < 8; ++t)
            cm = fmaxf(cm, fmaxf(fmaxf(st[t][0], st[t][1]),
                                 fmaxf(st[t][2], st[t][3])));
        cm = fmaxf(cm, __shfl_xor(cm, 16));
        cm = fmaxf(cm, __shfl_xor(cm, 32));
        float mn    = fmaxf(m, cm);
        float alpha = __builtin_amdgcn_exp2f((m - mn) * C);
        m = mn;
        l *= alpha;
        // o rows are q = quad*4+reg -> fetch matching alpha from lanes 0..15
#pragma unroll
        for (int reg = 0; reg < 4; ++reg) {
            float ar = __shfl(alpha, quad * 4 + reg);
            o0[reg] *= ar;
            o1[reg] *= ar;
        }

        float ls = 0.f;
#pragma unroll
        for (int t = 0; t < 8; ++t) {
            ushort4 pk;
            float p0 = __builtin_amdgcn_exp2f((st[t][0] - mn) * C);
            float p1 = __builtin_amdgcn_exp2f((st[t][1] - mn) * C);
            float p2 = __builtin_amdgcn_exp2f((st[t][2] - mn) * C);
            float p3 = __builtin_amdgcn_exp2f((st[t][3] - mn) * C);
            ls += (p0 + p1) + (p2 + p3);
            pk.x = f2bf(p0); pk.y = f2bf(p1); pk.z = f2bf(p2); pk.w = f2bf(p3);
            // P[q=lq][seq = t*16 + quad*4 .. +3]
            *(ushort4*)&Pw[lq * P_STRIDE + t * 16 + quad * 4] = pk;
        }
        ls += __shfl_xor(ls, 16);
        ls += __shfl_xor(ls, 32);
        l += ls;

        // ---- PV: O[16q,32dh] += P[16,128] x V[128,32] ----
#pragma unroll
        for (int s = 0; s < 4; ++s) {
            bf16x8 pf = *(const bf16x8*)&Pw[lq * P_STRIDE + s * 32 + quad * 8];
            bf16x8 v0 = *(const bf16x8*)&VsT[lq        * VT_STRIDE + s * 32 + quad * 8];
            bf16x8 v1 = *(const bf16x8*)&VsT[(16 + lq) * VT_STRIDE + s * 32 + quad * 8];
            o0 = __builtin_amdgcn_mfma_f32_16x16x32_bf16(pf, v0, o0, 0, 0, 0);
            o1 = __builtin_amdgcn_mfma_f32_16x16x32_bf16(pf, v1, o1, 0, 0, 0);
        }
    }

    // ---- epilogue: divide by per-row l, write fp32 [b][n][d] ----
#pragma unroll
    for (int reg = 0; reg < 4; ++reg) {
        float lr  = __shfl(l, quad * 4 + reg);
        float inv = 1.0f / lr;
        int   qg  = q0 + quad * 4 + reg;
        float* dst = a_ws + ((size_t)b * SEQ + qg) * DMODEL + h * DH;
        dst[lq]      = o0[reg] * inv;
        dst[16 + lq] = o1[reg] * inv;
    }
}

// ---------------------------------------------------------------------------
// Kernel 3: output projection (fp32, unchanged).
// ---------------------------------------------------------------------------
__global__ __launch_bounds__(256) void out_gemm(
    const float* __restrict__ a, const float* __restrict__ w,
    const float* __restrict__ bias, float* __restrict__ out)
{
    __shared__ float At[32][132];
    __shared__ float Bs[32][64];
    const int tid  = threadIdx.x;
    const int tx   = tid & 15;
    const int ty   = tid >> 4;
    const int row0 = blockIdx.y * 128;
    const int col0 = blockIdx.x * 64;

    float acc[8][4];
#pragma unroll
    for (int i = 0; i < 8; ++i)
#pragma unroll
        for (int j = 0; j < 4; ++j) acc[i][j] = 0.f;

    for (int k0 = 0; k0 < DMODEL; k0 += 32) {
        __syncthreads();
#pragma unroll
        for (int jj = 0; jj < 4; ++jj) {
            int f  = tid + 256 * jj;
            int rl = f >> 3;
            int c4 = (f & 7) << 2;
            float4 t = *(const float4*)(a + (size_t)(row0 + rl) * DMODEL + k0 + c4);
            At[c4 + 0][rl] = t.x; At[c4 + 1][rl] = t.y;
            At[c4 + 2][rl] = t.z; At[c4 + 3][rl] = t.w;
        }
#pragma unroll
        for (int jj = 0; jj < 2; ++jj) {
            int f  = tid + 256 * jj;
            int rl = f >> 4;
            int c4 = (f & 15) << 2;
            *(float4*)&Bs[rl][c4] =
                *(const float4*)(w + (size_t)(k0 + rl) * DMODEL + col0 + c4);
        }
        __syncthreads();
#pragma unroll
        for (int kk = 0; kk < 32; ++kk) {
            float4 a0 = *(const float4*)&At[kk][ty * 8];
            float4 a1 = *(const float4*)&At[kk][ty * 8 + 4];
            float4 b  = *(const float4*)&Bs[kk][tx * 4];
            float av[8] = {a0.x, a0.y, a0.z, a0.w, a1.x, a1.y, a1.z, a1.w};
            float bv[4] = {b.x, b.y, b.z, b.w};
#pragma unroll
            for (int i = 0; i < 8; ++i)
#pragma unroll
                for (int j = 0; j < 4; ++j) acc[i][j] += av[i] * bv[j];
        }
    }
#pragma unroll
    for (int i = 0; i < 8; ++i) {
        int grow = row0 + ty * 8 + i;
        int col  = col0 + tx * 4;
        float4 t;
        t.x = acc[i][0] + bias[col + 0];
        t.y = acc[i][1] + bias[col + 1];
        t.z = acc[i][2] + bias[col + 2];
        t.w = acc[i][3] + bias[col + 3];
        *(float4*)(out + (size_t)grow * DMODEL + col) = t;
    }
}

extern "C" void kernel_launch(void* const* d_in, const int* in_sizes, int n_in,
                              void* d_out, int out_size, void* d_ws, size_t ws_size,
                              hipStream_t stream) {
    const float* x     = (const float*)d_in[0];
    const float* w_qkv = (const float*)d_in[1];
    const float* b_qkv = (const float*)d_in[2];
    const float* w_out = (const float*)d_in[3];
    const float* b_out = (const float*)d_in[4];
    float* out = (float*)d_out;

    const size_t TSZ = (size_t)MTOT * DMODEL;           // 2,097,152 elems
    __hip_bfloat16* q_ws = (__hip_bfloat16*)d_ws;       // 4 MiB
    __hip_bfloat16* k_ws = q_ws + TSZ;                  // 4 MiB
    __hip_bfloat16* v_ws = k_ws + TSZ;                  // 4 MiB  (V^T layout)
    float*          a_ws = (float*)(v_ws + TSZ);        // 32 MiB fp32

    qkv_gemm<<<dim3(768 / 64, MTOT / 128), 256, 0, stream>>>(
        x, w_qkv, b_qkv, q_ws, k_ws, v_ws);
    attn_mfma<<<dim3(SEQ / 64, NH, BATCH), 256, 0, stream>>>(
        (const ushort*)q_ws, (const ushort*)k_ws, (const ushort*)v_ws, a_ws);
    out_gemm<<<dim3(DMODEL / 64, MTOT / 128), 256, 0, stream>>>(
        a_ws, w_out, b_out, out);
}

// Round 3
// 141.531 us; speedup vs baseline: 4.1843x; 1.2814x over previous
//
#include <hip/hip_runtime.h>
#include <hip/hip_bf16.h>
#include <math.h>

#define BATCH  4
#define SEQ    2048
#define DMODEL 256
#define NH     8
#define DH     32
#define MTOT   (BATCH*SEQ)   // 8192

typedef short  bf16x8 __attribute__((ext_vector_type(8)));   // 8 bf16 = 4 VGPRs
typedef float  f32x4  __attribute__((ext_vector_type(4)));

static __device__ __forceinline__ ushort f2bf(float f) {
    __hip_bfloat16 h = __float2bfloat16(f);   // RNE
    return __builtin_bit_cast(ushort, h);
}

// ---------------------------------------------------------------------------
// Kernel 0: weight convert+transpose.  w[k=256][N] fp32 -> wT[N][256] bf16.
// 32x32 LDS tile, 256 threads.
// ---------------------------------------------------------------------------
__global__ __launch_bounds__(256) void wcvt_t(
    const float* __restrict__ w, ushort* __restrict__ wT, int N)
{
    __shared__ float T[32][33];
    const int t  = threadIdx.x;
    const int n0 = blockIdx.x * 32, k0 = blockIdx.y * 32;
    {
        int tr = t >> 3, tc = (t & 7) * 4;
        *(float4*)&T[tr][tc] = *(const float4*)(w + (size_t)(k0 + tr) * N + n0 + tc);
    }
    __syncthreads();
    int nl = t >> 3, kq = (t & 7) * 4;
    ushort4 pk;
    pk.x = f2bf(T[kq + 0][nl]); pk.y = f2bf(T[kq + 1][nl]);
    pk.z = f2bf(T[kq + 2][nl]); pk.w = f2bf(T[kq + 3][nl]);
    *(ushort4*)&wT[(size_t)(n0 + nl) * 256 + k0 + kq] = pk;
}

// ---------------------------------------------------------------------------
// Kernel 1: QKV projection, bf16 MFMA.  x[8192,256] fp32 (inline cvt) @
// wqT[768,256] bf16 + bias.  Tile 128x128, BK=32, 4 waves (2x2, 64x64 each).
// Q/K blocks (bx<4): swapped mfma -> C rows = n(dh)  -> ushort4 into [b,h,s,dh].
// V blocks  (bx>=4): normal  mfma -> C rows = m(seq) -> ushort4 into V^T [b,h,dh,s].
// LDS row stride 40 ushorts: minimum bank conflicts for b128 write+read.
// ---------------------------------------------------------------------------
#define LS 40

__global__ __launch_bounds__(256) void qkv_gemm(
    const float* __restrict__ x, const ushort* __restrict__ wT,
    const float* __restrict__ bias,
    ushort* __restrict__ qo, ushort* __restrict__ ko, ushort* __restrict__ vo)
{
    __shared__ ushort As[128 * LS];
    __shared__ ushort Bs[128 * LS];
    const int tid  = threadIdx.x;
    const int wid  = tid >> 6;
    const int lane = tid & 63;
    const int lq   = lane & 15;
    const int quad = lane >> 4;
    const int wm   = wid & 1;        // m 64-span
    const int wn   = wid >> 1;       // n 64-span
    const int m0   = blockIdx.y * 128;
    const int n0   = blockIdx.x * 128;
    const bool isV = (blockIdx.x >= 4);

    const int ar = tid >> 1;             // A-stage row 0..127
    const int ak = (tid & 1) * 16;       // A-stage k offset
    const float*  agp = x  + (size_t)(m0 + ar) * 256 + ak;
    const ushort* bgp = wT + (size_t)(n0 + ar) * 256 + ak;

    f32x4 acc[4][4];
#pragma unroll
    for (int i = 0; i < 4; ++i)
#pragma unroll
        for (int j = 0; j < 4; ++j) acc[i][j] = {0.f, 0.f, 0.f, 0.f};

    for (int k0 = 0; k0 < 256; k0 += 32) {
        __syncthreads();
#pragma unroll
        for (int i = 0; i < 2; ++i) {    // A: fp32 -> bf16
            float4 f0 = *(const float4*)(agp + k0 + i * 8);
            float4 f1 = *(const float4*)(agp + k0 + i * 8 + 4);
            ushort4 lo, hi;
            lo.x = f2bf(f0.x); lo.y = f2bf(f0.y); lo.z = f2bf(f0.z); lo.w = f2bf(f0.w);
            hi.x = f2bf(f1.x); hi.y = f2bf(f1.y); hi.z = f2bf(f1.z); hi.w = f2bf(f1.w);
            *(ushort4*)&As[ar * LS + ak + i * 8]     = lo;
            *(ushort4*)&As[ar * LS + ak + i * 8 + 4] = hi;
        }
#pragma unroll
        for (int i = 0; i < 2; ++i) {    // B: bf16 copy
            *(uint4*)&Bs[ar * LS + ak + i * 8] =
                *(const uint4*)(bgp + k0 + i * 8);
        }
        __syncthreads();

        bf16x8 af[4], bfg[4];
#pragma unroll
        for (int mi = 0; mi < 4; ++mi)
            af[mi]  = *(const bf16x8*)&As[(wm * 64 + mi * 16 + lq) * LS + quad * 8];
#pragma unroll
        for (int ni = 0; ni < 4; ++ni)
            bfg[ni] = *(const bf16x8*)&Bs[(wn * 64 + ni * 16 + lq) * LS + quad * 8];

        if (isV) {
#pragma unroll
            for (int mi = 0; mi < 4; ++mi)
#pragma unroll
                for (int ni = 0; ni < 4; ++ni)
                    acc[mi][ni] = __builtin_amdgcn_mfma_f32_16x16x32_bf16(
                        af[mi], bfg[ni], acc[mi][ni], 0, 0, 0);
        } else {
#pragma unroll
            for (int ni = 0; ni < 4; ++ni)
#pragma unroll
                for (int mi = 0; mi < 4; ++mi)
                    acc[ni][mi] = __builtin_amdgcn_mfma_f32_16x16x32_bf16(
                        bfg[ni], af[mi], acc[ni][mi], 0, 0, 0);
        }
    }

    if (!isV) {
        // C rows = n (4 consecutive dh per lane), cols = m (seq = lq-indexed)
#pragma unroll
        for (int ni = 0; ni < 4; ++ni) {
            int nb = n0 + wn * 64 + ni * 16 + quad * 4;
            float4 bs = *(const float4*)(bias + nb);
            int h   = (nb >> 5) & 7;
            int dh0 = nb & 31;
            ushort* dst = (nb < 256) ? qo : ko;
#pragma unroll
            for (int mi = 0; mi < 4; ++mi) {
                int m   = m0 + wm * 64 + mi * 16 + lq;
                int b   = m >> 11, seq = m & 2047;
                f32x4 c = acc[ni][mi];
                ushort4 pk;
                pk.x = f2bf(c[0] + bs.x); pk.y = f2bf(c[1] + bs.y);
                pk.z = f2bf(c[2] + bs.z); pk.w = f2bf(c[3] + bs.w);
                *(ushort4*)&dst[(((size_t)b * NH + h) * SEQ + seq) * DH + dh0] = pk;
            }
        }
    } else {
        // C rows = m (4 consecutive seq per lane), cols = n (dh = lq-indexed)
#pragma unroll
        for (int ni = 0; ni < 4; ++ni) {
            int n  = n0 + wn * 64 + ni * 16 + lq;
            int h  = (n >> 5) & 7;
            int dh = n & 31;
            float bsc = bias[n];
#pragma unroll
            for (int mi = 0; mi < 4; ++mi) {
                int mb  = m0 + wm * 64 + mi * 16 + quad * 4;
                int b   = mb >> 11, seq = mb & 2047;
                f32x4 c = acc[mi][ni];
                ushort4 pk;
                pk.x = f2bf(c[0] + bsc); pk.y = f2bf(c[1] + bsc);
                pk.z = f2bf(c[2] + bsc); pk.w = f2bf(c[3] + bsc);
                *(ushort4*)&vo[(((size_t)b * NH + h) * DH + dh) * SEQ + seq] = pk;
            }
        }
    }
}

// ---------------------------------------------------------------------------
// Kernel 2: MFMA flash attention, O^T form.  4 waves/block, 16 q-rows/wave.
// S^T = K·Q^T (C: row=seq, col=q=lq)  ->  softmax state keyed by lq.
// PV swapped: O^T = V^T·P^T (C: row=dh, col=q=lq) -> alpha & 1/l applied
// directly per-lane, NO broadcast shuffles (only 4 xor-butterflies per kt).
// Output bf16 [b,n,d] for the MFMA out-projection.
// ---------------------------------------------------------------------------
#define KS_STRIDE 40
#define VT_STRIDE 136
#define P_STRIDE  136

__global__ __launch_bounds__(256, 4) void attn_mfma(
    const ushort* __restrict__ qb, const ushort* __restrict__ kb,
    const ushort* __restrict__ vtb, ushort* __restrict__ a_bf)
{
    __shared__ ushort Ks[128 * KS_STRIDE];
    __shared__ ushort VsT[32 * VT_STRIDE];
    __shared__ ushort Pl[4 * 16 * P_STRIDE];

    const int tid  = threadIdx.x;
    const int wid  = tid >> 6;
    const int lane = tid & 63;
    const int lq   = lane & 15;
    const int quad = lane >> 4;
    const int h    = blockIdx.y;
    const int b    = blockIdx.z;
    const int bh   = b * NH + h;
    const int q0   = blockIdx.x * 64 + wid * 16;

    const ushort* qrow = qb + ((size_t)bh * SEQ + q0 + lq) * DH + quad * 8;
    const bf16x8 qf = *(const bf16x8*)qrow;

    const ushort* kbase  = kb  + (size_t)bh * SEQ * DH;
    const ushort* vtbase = vtb + (size_t)bh * DH * SEQ;
    ushort* Pw = Pl + wid * 16 * P_STRIDE;

    f32x4 o0 = {0.f, 0.f, 0.f, 0.f};
    f32x4 o1 = {0.f, 0.f, 0.f, 0.f};
    float m = -1e30f, l = 0.f;
    const float C = 0.09016844005556021f;   // 256^-0.5 * log2(e)

    for (int kt = 0; kt < SEQ; kt += 128) {
        __syncthreads();
#pragma unroll
        for (int jj = 0; jj < 2; ++jj) {
            int f = tid + 256 * jj;
            {   // K: 128 x 32
                int r  = f >> 2;
                int c8 = (f & 3) * 8;
                *(bf16x8*)&Ks[r * KS_STRIDE + c8] =
                    *(const bf16x8*)(kbase + (size_t)(kt + r) * DH + c8);
            }
            {   // V^T: 32 x 128
                int dh = f >> 4;
                int c8 = (f & 15) * 8;
                *(bf16x8*)&VsT[dh * VT_STRIDE + c8] =
                    *(const bf16x8*)(vtbase + (size_t)dh * SEQ + kt + c8);
            }
        }
        __syncthreads();

        // ---- S^T tiles ----
        f32x4 st[8];
#pragma unroll
        for (int t = 0; t < 8; ++t) {
            bf16x8 kf = *(const bf16x8*)&Ks[(t * 16 + lq) * KS_STRIDE + quad * 8];
            f32x4 z = {0.f, 0.f, 0.f, 0.f};
            st[t] = __builtin_amdgcn_mfma_f32_16x16x32_bf16(kf, qf, z, 0, 0, 0);
        }

        // ---- online softmax (state per q = lq, identical in all 4 quads) ----
        float cm = -1e30f;
#pragma unroll
        for (int t = 0; t < 8; ++t)
            cm = fmaxf(cm, fmaxf(fmaxf(st[t][0], st[t][1]),
                                 fmaxf(st[t][2], st[t][3])));
        cm = fmaxf(cm, __shfl_xor(cm, 16));
        cm = fmaxf(cm, __shfl_xor(cm, 32));
        float mn    = fmaxf(m, cm);
        float alpha = __builtin_amdgcn_exp2f((m - mn) * C);
        m = mn;
        l *= alpha;
#pragma unroll
        for (int reg = 0; reg < 4; ++reg) { o0[reg] *= alpha; o1[reg] *= alpha; }

        float ls = 0.f;
#pragma unroll
        for (int t = 0; t < 8; ++t) {
            float p0 = __builtin_amdgcn_exp2f((st[t][0] - mn) * C);
            float p1 = __builtin_amdgcn_exp2f((st[t][1] - mn) * C);
            float p2 = __builtin_amdgcn_exp2f((st[t][2] - mn) * C);
            float p3 = __builtin_amdgcn_exp2f((st[t][3] - mn) * C);
            ls += (p0 + p1) + (p2 + p3);
            ushort4 pk;
            pk.x = f2bf(p0); pk.y = f2bf(p1); pk.z = f2bf(p2); pk.w = f2bf(p3);
            *(ushort4*)&Pw[lq * P_STRIDE + t * 16 + quad * 4] = pk;
        }
        ls += __shfl_xor(ls, 16);
        ls += __shfl_xor(ls, 32);
        l += ls;

        // ---- PV (O^T): o = mfma(V^T-frag, P^T-frag, o) ----
#pragma unroll
        for (int s = 0; s < 4; ++s) {
            bf16x8 pf = *(const bf16x8*)&Pw[lq * P_STRIDE + s * 32 + quad * 8];
            bf16x8 v0 = *(const bf16x8*)&VsT[lq        * VT_STRIDE + s * 32 + quad * 8];
            bf16x8 v1 = *(const bf16x8*)&VsT[(16 + lq) * VT_STRIDE + s * 32 + quad * 8];
            o0 = __builtin_amdgcn_mfma_f32_16x16x32_bf16(v0, pf, o0, 0, 0, 0);
            o1 = __builtin_amdgcn_mfma_f32_16x16x32_bf16(v1, pf, o1, 0, 0, 0);
        }
    }

    // ---- epilogue: per-lane 1/l (q = lq), bf16 out [b,n,d] ----
    float inv = 1.0f / l;
    ushort* dst = a_bf + ((size_t)b * SEQ + q0 + lq) * DMODEL + h * DH;
    ushort4 w0, w1;
    w0.x = f2bf(o0[0] * inv); w0.y = f2bf(o0[1] * inv);
    w0.z = f2bf(o0[2] * inv); w0.w = f2bf(o0[3] * inv);
    w1.x = f2bf(o1[0] * inv); w1.y = f2bf(o1[1] * inv);
    w1.z = f2bf(o1[2] * inv); w1.w = f2bf(o1[3] * inv);
    *(ushort4*)&dst[quad * 4]      = w0;
    *(ushort4*)&dst[16 + quad * 4] = w1;
}

// ---------------------------------------------------------------------------
// Kernel 3: out projection, bf16 MFMA.  a_bf[8192,256] @ woT[256,256] + bias
// -> fp32 out.  Tile 128x64, 4 waves (2x2: 64m x 32n each).  Swapped mfma:
// C rows = n -> float4 stores.
// ---------------------------------------------------------------------------
__global__ __launch_bounds__(256) void out_gemm(
    const ushort* __restrict__ a, const ushort* __restrict__ wT,
    const float* __restrict__ bias, float* __restrict__ out)
{
    __shared__ ushort As[128 * LS];
    __shared__ ushort Bs[64 * LS];
    const int tid  = threadIdx.x;
    const int wid  = tid >> 6;
    const int lane = tid & 63;
    const int lq   = lane & 15;
    const int quad = lane >> 4;
    const int wm   = wid & 1;
    const int wn   = wid >> 1;
    const int m0   = blockIdx.y * 128;
    const int n0   = blockIdx.x * 64;

    const int ar = tid >> 1;
    const int ak = (tid & 1) * 16;
    const ushort* agp = a  + (size_t)(m0 + ar) * 256 + ak;
    const int br  = tid >> 2;
    const int bk8 = (tid & 3) * 8;
    const ushort* bgp = wT + (size_t)(n0 + br) * 256 + bk8;

    f32x4 acc[2][4];
#pragma unroll
    for (int i = 0; i < 2; ++i)
#pragma unroll
        for (int j = 0; j < 4; ++j) acc[i][j] = {0.f, 0.f, 0.f, 0.f};

    for (int k0 = 0; k0 < 256; k0 += 32) {
        __syncthreads();
#pragma unroll
        for (int i = 0; i < 2; ++i)
            *(uint4*)&As[ar * LS + ak + i * 8] = *(const uint4*)(agp + k0 + i * 8);
        *(uint4*)&Bs[br * LS + bk8] = *(const uint4*)(bgp + k0);
        __syncthreads();

        bf16x8 af[4], bfg[2];
#pragma unroll
        for (int mi = 0; mi < 4; ++mi)
            af[mi]  = *(const bf16x8*)&As[(wm * 64 + mi * 16 + lq) * LS + quad * 8];
#pragma unroll
        for (int ni = 0; ni < 2; ++ni)
            bfg[ni] = *(const bf16x8*)&Bs[(wn * 32 + ni * 16 + lq) * LS + quad * 8];
#pragma unroll
        for (int ni = 0; ni < 2; ++ni)
#pragma unroll
            for (int mi = 0; mi < 4; ++mi)
                acc[ni][mi] = __builtin_amdgcn_mfma_f32_16x16x32_bf16(
                    bfg[ni], af[mi], acc[ni][mi], 0, 0, 0);
    }

#pragma unroll
    for (int ni = 0; ni < 2; ++ni) {
        int nb = n0 + wn * 32 + ni * 16 + quad * 4;
        float4 bs = *(const float4*)(bias + nb);
#pragma unroll
        for (int mi = 0; mi < 4; ++mi) {
            int m = m0 + wm * 64 + mi * 16 + lq;
            f32x4 c = acc[ni][mi];
            float4 o;
            o.x = c[0] + bs.x; o.y = c[1] + bs.y;
            o.z = c[2] + bs.z; o.w = c[3] + bs.w;
            *(float4*)&out[(size_t)m * DMODEL + nb] = o;
        }
    }
}

extern "C" void kernel_launch(void* const* d_in, const int* in_sizes, int n_in,
                              void* d_out, int out_size, void* d_ws, size_t ws_size,
                              hipStream_t stream) {
    const float* x     = (const float*)d_in[0];
    const float* w_qkv = (const float*)d_in[1];
    const float* b_qkv = (const float*)d_in[2];
    const float* w_out = (const float*)d_in[3];
    const float* b_out = (const float*)d_in[4];
    float* out = (float*)d_out;

    const size_t TSZ = (size_t)MTOT * DMODEL;        // 2,097,152 bf16 elems
    ushort* q_ws = (ushort*)d_ws;                    // 4 MiB
    ushort* k_ws = q_ws + TSZ;                       // 4 MiB
    ushort* v_ws = k_ws + TSZ;                       // 4 MiB (V^T [b,h,dh,seq])
    ushort* a_bf = v_ws + TSZ;                       // 4 MiB (attn out bf16)
    ushort* wqT  = a_bf + TSZ;                       // 768x256 bf16
    ushort* woT  = wqT + 768 * 256;                  // 256x256 bf16

    wcvt_t<<<dim3(24, 8), 256, 0, stream>>>(w_qkv, wqT, 768);
    wcvt_t<<<dim3(8, 8),  256, 0, stream>>>(w_out, woT, 256);
    qkv_gemm<<<dim3(6, 64), 256, 0, stream>>>(x, wqT, b_qkv, q_ws, k_ws, v_ws);
    attn_mfma<<<dim3(SEQ / 64, NH, BATCH), 256, 0, stream>>>(
        q_ws, k_ws, v_ws, a_bf);
    out_gemm<<<dim3(4, 64), 256, 0, stream>>>(a_bf, woT, b_out, out);
}